// Round 9
// baseline (254.363 us; speedup 1.0000x reference)
//
#include <hip/hip_runtime.h>
#include <hip/hip_bf16.h>

typedef __bf16 bf16;
typedef __bf16 bf16x4 __attribute__((ext_vector_type(4)));
typedef __bf16 bf16x8 __attribute__((ext_vector_type(8)));
typedef float floatx4 __attribute__((ext_vector_type(4)));

#define B_ 2
#define T_ 2048
#define C_ 1024
#define H_ 16
#define D_ 64
#define M_ 4096
#define QK_LD 2048
#define NSLOT 36  /* partial-O slots per bh: qb4-7 x2 + qb8-11 x3 + qb12-15 x4 */

__device__ __forceinline__ void load_lds16(const void* g, void* l) {
  __builtin_amdgcn_global_load_lds(
      (const __attribute__((address_space(1))) unsigned int*)g,
      (__attribute__((address_space(3))) unsigned int*)l, 16, 0, 0);
}

__device__ __forceinline__ int poff(int qb) {
  return (qb < 8) ? (qb - 4) * 2 : (qb < 12) ? 8 + (qb - 8) * 3 : 20 + (qb - 12) * 4;
}

// --------------------------- prep: weight transposes + x convert (one launch)
struct PrepArgs { const float* w[4]; bf16* wt[4]; const float* x; bf16* xb; };

__global__ __launch_bounds__(256)
void prep(PrepArgs p) {
  const int bid = blockIdx.x;
  if (bid < 4096) {
    __shared__ float tile[32][33];
    const int z = bid >> 10, xy = bid & 1023;
    const int bx = xy & 31, by = xy >> 5;
    const float* in = p.w[z];
    bf16* out = p.wt[z];
    int tx = threadIdx.x & 31, ty = threadIdx.x >> 5;
    int n0 = bx * 32, k0 = by * 32;
#pragma unroll
    for (int j = 0; j < 32; j += 8)
      tile[ty + j][tx] = in[(size_t)(k0 + ty + j) * C_ + n0 + tx];
    __syncthreads();
#pragma unroll
    for (int j = 0; j < 32; j += 8)
      out[(size_t)(n0 + ty + j) * C_ + k0 + tx] = (bf16)tile[tx][ty + j];
  } else {
    int i = ((bid - 4096) * 256 + threadIdx.x) * 8;
    float4 a = *(const float4*)(p.x + i);
    float4 b = *(const float4*)(p.x + i + 4);
    bf16x8 o;
    o[0] = (bf16)a.x; o[1] = (bf16)a.y; o[2] = (bf16)a.z; o[3] = (bf16)a.w;
    o[4] = (bf16)b.x; o[5] = (bf16)b.y; o[6] = (bf16)b.z; o[7] = (bf16)b.w;
    *(bf16x8*)(p.xb + i) = o;
  }
}

// ---------------------------------------------------------------- QKV GEMM
struct GQ {
  const bf16* A; const bf16* Bt;
  const float* bias[3];
  bf16* Cout; bf16* vt; int N; int K;
};

__global__ __launch_bounds__(256, 2)
void gemm128(GQ g) {
  __shared__ __align__(16) bf16 As[128 * 64];
  __shared__ __align__(16) bf16 Bs[128 * 64];
  const int tid = threadIdx.x;
  const int wave = tid >> 6, lane = tid & 63;
  const int quad = lane >> 4, l16 = lane & 15;
  const int m0 = blockIdx.y * 128, n0 = blockIdx.x * 128;
  const int wm = (wave >> 1) * 64, wn = (wave & 1) * 64;

  floatx4 acc[4][4] = {};

  int rA[4], cA[4];
#pragma unroll
  for (int t = 0; t < 4; ++t) {
    int pch = (wave * 4 + t) * 64 + lane;
    rA[t] = pch >> 3;
    cA[t] = (pch & 7) ^ (rA[t] & 7);
  }

  for (int k0 = 0; k0 < g.K; k0 += 64) {
    __syncthreads();
#pragma unroll
    for (int t = 0; t < 4; ++t) {
      load_lds16(g.A + (size_t)(m0 + rA[t]) * g.K + k0 + cA[t] * 8,
                 As + (wave * 4 + t) * 512);
      load_lds16(g.Bt + (size_t)(n0 + rA[t]) * g.K + k0 + cA[t] * 8,
                 Bs + (wave * 4 + t) * 512);
    }
    __builtin_amdgcn_s_waitcnt(0x0f70);
    __syncthreads();
#pragma unroll
    for (int s = 0; s < 2; ++s) {
      bf16x8 af[4], bfr[4];
#pragma unroll
      for (int i = 0; i < 4; ++i) {
        int mr = wm + i * 16 + l16;
        af[i] = *(const bf16x8*)(As + ((mr * 8) + ((s * 4 + quad) ^ (mr & 7))) * 8);
        int nr = wn + i * 16 + l16;
        bfr[i] = *(const bf16x8*)(Bs + ((nr * 8) + ((s * 4 + quad) ^ (nr & 7))) * 8);
      }
#pragma unroll
      for (int i = 0; i < 4; ++i)
#pragma unroll
        for (int j = 0; j < 4; ++j)
          acc[i][j] = __builtin_amdgcn_mfma_f32_16x16x32_bf16(af[i], bfr[j],
                                                              acc[i][j], 0, 0, 0);
    }
  }

  const bool vsplit = (n0 >= 2048);
#pragma unroll
  for (int j = 0; j < 4; ++j) {
    int col = n0 + wn + j * 16 + l16;
    const float* bp = g.bias[col >> 10];
    float bv = bp[col & 1023];
    if (vsplit) {
      int cv = col - 2048;  // cv = h*64 + d
      bf16* dst0 = g.vt + ((size_t)((m0 >> 11) * 16 + (cv >> 6)) * 64 + (cv & 63)) * (size_t)T_
                   + (m0 & 2047) + wm + quad * 4;
#pragma unroll
      for (int i = 0; i < 4; ++i) {
        bf16x4 pk;
#pragma unroll
        for (int r = 0; r < 4; ++r) pk[r] = (bf16)(acc[i][j][r] + bv);
        *(bf16x4*)(dst0 + i * 16) = pk;
      }
    } else {
#pragma unroll
      for (int i = 0; i < 4; ++i) {
#pragma unroll
        for (int r = 0; r < 4; ++r) {
          int row = m0 + wm + i * 16 + quad * 4 + r;
          g.Cout[(size_t)row * g.N + col] = (bf16)(acc[i][j][r] + bv);
        }
      }
    }
  }
}

// ---------------------------------------------------------------- out GEMM
__global__ __launch_bounds__(256, 2)
void gemm_out(const bf16* __restrict__ A, const bf16* __restrict__ Bt,
              const float* __restrict__ bias, float* __restrict__ C) {
  __shared__ __align__(16) bf16 As[64 * 64];
  __shared__ __align__(16) bf16 Bs[128 * 64];
  const int tid = threadIdx.x;
  const int wave = tid >> 6, lane = tid & 63;
  const int quad = lane >> 4, l16 = lane & 15;
  const int m0 = blockIdx.y * 64, n0 = blockIdx.x * 128;
  const int wm = (wave >> 1) * 32, wn = (wave & 1) * 64;

  floatx4 acc[2][4] = {};

  int rA[2], cA[2], rB[4], cB[4];
#pragma unroll
  for (int t = 0; t < 2; ++t) {
    int p = t * 256 + tid;
    rA[t] = p >> 3; cA[t] = (p & 7) ^ (rA[t] & 7);
  }
#pragma unroll
  for (int t = 0; t < 4; ++t) {
    int p = t * 256 + tid;
    rB[t] = p >> 3; cB[t] = (p & 7) ^ (rB[t] & 7);
  }

  for (int k0 = 0; k0 < 1024; k0 += 64) {
    __syncthreads();
#pragma unroll
    for (int t = 0; t < 2; ++t)
      load_lds16(A + (size_t)(m0 + rA[t]) * 1024 + k0 + cA[t] * 8,
                 As + t * 2048 + wave * 512);
#pragma unroll
    for (int t = 0; t < 4; ++t)
      load_lds16(Bt + (size_t)(n0 + rB[t]) * 1024 + k0 + cB[t] * 8,
                 Bs + t * 2048 + wave * 512);
    __builtin_amdgcn_s_waitcnt(0x0f70);
    __syncthreads();
#pragma unroll
    for (int s = 0; s < 2; ++s) {
      bf16x8 af[2], bfr[4];
#pragma unroll
      for (int i = 0; i < 2; ++i) {
        int mr = wm + i * 16 + l16;
        af[i] = *(const bf16x8*)(As + ((mr * 8) + ((s * 4 + quad) ^ (mr & 7))) * 8);
      }
#pragma unroll
      for (int j = 0; j < 4; ++j) {
        int nr = wn + j * 16 + l16;
        bfr[j] = *(const bf16x8*)(Bs + ((nr * 8) + ((s * 4 + quad) ^ (nr & 7))) * 8);
      }
#pragma unroll
      for (int i = 0; i < 2; ++i)
#pragma unroll
        for (int j = 0; j < 4; ++j)
          acc[i][j] = __builtin_amdgcn_mfma_f32_16x16x32_bf16(af[i], bfr[j],
                                                              acc[i][j], 0, 0, 0);
    }
  }

#pragma unroll
  for (int j = 0; j < 4; ++j) {
    int col = n0 + wn + j * 16 + l16;
    float bv = bias[col];
#pragma unroll
    for (int i = 0; i < 2; ++i)
#pragma unroll
      for (int r = 0; r < 4; ++r) {
        int row = m0 + wm + i * 16 + quad * 4 + r;
        C[(size_t)row * 1024 + col] = acc[i][j][r] + bv;
      }
  }
}

// ---------------------------------------------------------------- attention
// FIXED-MAX streaming softmax: with the per-row ALiBi constant retained,
// scores (log2-domain) are bounded by ~+3, so P = exp2(v - 14) needs no
// running max: no shuffle reduce, no alpha rescale, no m-state.
// grid (32 bh, 40): every q-tile split into ceil((2qb+2)/8) segments of <=8
// k-tiles -> 1280 near-uniform blocks, 3/CU co-resident + deep backfill.
// l-state rides a 5th accumulator via a ones B-fragment.
__global__ __launch_bounds__(256, 3)
void attn6(const bf16* __restrict__ qk, const bf16* __restrict__ vt,
           bf16* __restrict__ y, bf16* __restrict__ po, float* __restrict__ pl) {
  __shared__ __align__(16) bf16 Kl[2][64 * 64];
  __shared__ __align__(16) bf16 Vl[2][64 * 64];
  __shared__ __align__(16) bf16 Pl[4][16 * 68];
  const int tid = threadIdx.x, wave = tid >> 6, lane = tid & 63;
  const int quad = lane >> 4, l16 = lane & 15;
  const int bh = blockIdx.x, b = bh >> 4, h = bh & 15;
  const int yy = blockIdx.y;
  int qb, seg, nseg;
  if (yy < 4)       { qb = yy;                 seg = 0;            nseg = 1; }
  else if (yy < 12) { qb = 4 + ((yy - 4) >> 1); seg = (yy - 4) & 1; nseg = 2; }
  else if (yy < 24) { qb = 8 + (yy - 12) / 3;   seg = (yy - 12) % 3; nseg = 3; }
  else              { qb = 12 + ((yy - 24) >> 2); seg = (yy - 24) & 3; nseg = 4; }
  const int ktot = 2 * qb + 2;
  const int kb = ktot / nseg, krem = ktot - kb * nseg;
  const int kcnt = kb + (seg < krem ? 1 : 0);
  const int kbeg = seg * kb + (seg < krem ? seg : krem);

  const float L2E = 1.4426950408889634f;
  const float slope2 = exp2f(-0.5f * (float)(h + 1)) * L2E;  // log2-domain slope
  const float scl2 = 0.125f * L2E;
  const float M0 = 14.0f;  // fixed softmax max (log2 units); scores << 14

  bf16x8 ones;
  {
    bf16 v1 = (l16 == 0) ? (bf16)1.0f : (bf16)0.0f;
#pragma unroll
    for (int j = 0; j < 8; ++j) ones[j] = v1;
  }

  int rS[2], cS[2];
#pragma unroll
  for (int t = 0; t < 2; ++t) {
    int p = t * 256 + tid;
    rS[t] = p >> 3;
    cS[t] = (p & 7) ^ (rS[t] & 7);
  }
  const bf16* kbase = qk + (size_t)b * T_ * QK_LD + 1024 + h * 64;
  const bf16* vbase = vt + (size_t)bh * 64 * T_;

  bf16* Plw = Pl[wave];
  const int q0 = qb * 128;
  const int w0 = q0 + wave * 32;

  bf16x8 qf[2][2];
  float rowoff[2][4];
#pragma unroll
  for (int qt = 0; qt < 2; ++qt) {
#pragma unroll
    for (int s = 0; s < 2; ++s)
      qf[qt][s] = *(const bf16x8*)(qk +
          (size_t)(b * T_ + w0 + qt * 16 + l16) * QK_LD + h * 64 + s * 32 + quad * 8);
#pragma unroll
    for (int r = 0; r < 4; ++r)
      rowoff[qt][r] = slope2 * (float)(w0 + qt * 16 + quad * 4 + r) + M0;
  }

  floatx4 o[2][5];
#pragma unroll
  for (int qt = 0; qt < 2; ++qt)
#pragma unroll
    for (int n = 0; n < 5; ++n) o[qt][n] = (floatx4)0.f;

  // prologue: stage first tile into buffer 0
#pragma unroll
  for (int t = 0; t < 2; ++t) {
    load_lds16(kbase + (size_t)(kbeg * 64 + rS[t]) * QK_LD + cS[t] * 8,
               Kl[0] + (t * 4 + wave) * 512);
    load_lds16(vbase + (size_t)rS[t] * T_ + kbeg * 64 + cS[t] * 8,
               Vl[0] + (t * 4 + wave) * 512);
  }
  __builtin_amdgcn_s_waitcnt(0x0f70);
  __syncthreads();

  for (int it = 0; it < kcnt; ++it) {
    const int kj0 = (kbeg + it) * 64;
    const int cur = it & 1;

    if (it + 1 < kcnt) {
      const int nk = kj0 + 64;
#pragma unroll
      for (int t = 0; t < 2; ++t) {
        load_lds16(kbase + (size_t)(nk + rS[t]) * QK_LD + cS[t] * 8,
                   Kl[cur ^ 1] + (t * 4 + wave) * 512);
        load_lds16(vbase + (size_t)rS[t] * T_ + nk + cS[t] * 8,
                   Vl[cur ^ 1] + (t * 4 + wave) * 512);
      }
    }

    const bf16* Klc = Kl[cur];
    const bf16* Vlc = Vl[cur];
    bf16x8 kf[2][4], vf[2][4];
#pragma unroll
    for (int ss = 0; ss < 2; ++ss)
#pragma unroll
      for (int kt = 0; kt < 4; ++kt) {
        const int krow = kt * 16 + l16;
        kf[ss][kt] = *(const bf16x8*)(Klc + krow * 64 + (((ss * 4 + quad) ^ (krow & 7)) * 8));
        vf[ss][kt] = *(const bf16x8*)(Vlc + krow * 64 + (((ss * 4 + quad) ^ (krow & 7)) * 8));
      }

    float scol[4];
#pragma unroll
    for (int kt = 0; kt < 4; ++kt)
      scol[kt] = slope2 * (float)(kj0 + kt * 16 + l16);

#pragma unroll
    for (int qt = 0; qt < 2; ++qt) {
      const int rb = w0 + qt * 16;
      floatx4 sa[4] = {};
#pragma unroll
      for (int ss = 0; ss < 2; ++ss)
#pragma unroll
        for (int kt = 0; kt < 4; ++kt)
          sa[kt] = __builtin_amdgcn_mfma_f32_16x16x32_bf16(qf[qt][ss], kf[ss][kt],
                                                           sa[kt], 0, 0, 0);

      // P = exp2(scale*s + slope*(col-row) - M0); masked cols -> 0
      if (kj0 + 63 > rb) {
#pragma unroll
        for (int kt = 0; kt < 4; ++kt)
#pragma unroll
          for (int r = 0; r < 4; ++r) {
            const int row = rb + quad * 4 + r;
            float p = __builtin_amdgcn_exp2f(
                fmaf(sa[kt][r], scl2, scol[kt]) - rowoff[qt][r]);
            if (kj0 + kt * 16 + l16 > row) p = 0.f;
            Plw[(quad * 4 + r) * 68 + kt * 16 + l16] = (bf16)p;
          }
      } else {
#pragma unroll
        for (int kt = 0; kt < 4; ++kt)
#pragma unroll
          for (int r = 0; r < 4; ++r)
            Plw[(quad * 4 + r) * 68 + kt * 16 + l16] = (bf16)__builtin_amdgcn_exp2f(
                fmaf(sa[kt][r], scl2, scol[kt]) - rowoff[qt][r]);
      }

      __builtin_amdgcn_s_waitcnt(0xc07f);  // lgkmcnt(0): P visible in-wave

#pragma unroll
      for (int half = 0; half < 2; ++half) {
        bf16x8 pf = *(const bf16x8*)(Plw + l16 * 68 + half * 32 + quad * 8);
#pragma unroll
        for (int nt = 0; nt < 4; ++nt)
          o[qt][nt] = __builtin_amdgcn_mfma_f32_16x16x32_bf16(pf, vf[half][nt],
                                                              o[qt][nt], 0, 0, 0);
        o[qt][4] = __builtin_amdgcn_mfma_f32_16x16x32_bf16(pf, ones, o[qt][4], 0, 0, 0);
      }
    }

    __builtin_amdgcn_s_waitcnt(0x0f70);  // vmcnt(0): next tile landed
    __syncthreads();
  }

  if (nseg == 1) {
#pragma unroll
    for (int qt = 0; qt < 2; ++qt)
#pragma unroll
      for (int r = 0; r < 4; ++r) {
        float lsum = __shfl(o[qt][4][r], lane & 48);  // l16==0 lane of this quad
        float inv = 1.f / lsum;
        const int row = w0 + qt * 16 + quad * 4 + r;
#pragma unroll
        for (int nt = 0; nt < 4; ++nt)
          y[(size_t)(b * T_ + row) * C_ + h * 64 + nt * 16 + l16] =
              (bf16)(o[qt][nt][r] * inv);
      }
  } else {
    const int pid = bh * NSLOT + poff(qb) + seg;
    bf16* pob = po + (size_t)pid * 128 * 64;
#pragma unroll
    for (int qt = 0; qt < 2; ++qt)
#pragma unroll
      for (int r = 0; r < 4; ++r) {
        const int rl = wave * 32 + qt * 16 + quad * 4 + r;
#pragma unroll
        for (int nt = 0; nt < 4; ++nt)
          pob[rl * 64 + nt * 16 + l16] = (bf16)o[qt][nt][r];
        if (l16 == 0) pl[pid * 128 + rl] = o[qt][4][r];
      }
  }
}

// --------------------------------------------------- combine split segments
// grid 32*12: one block per (bh, qb in 4..15).  out = (sum o_s)/(sum l_s).
__global__ __launch_bounds__(256)
void combine(const bf16* __restrict__ po, const float* __restrict__ pl,
             bf16* __restrict__ y) {
  const int x = blockIdx.x;
  const int bh = x / 12, qb = (x - bh * 12) + 4;
  const int b = bh >> 4, h = bh & 15;
  const int nseg = (qb < 8) ? 2 : (qb < 12) ? 3 : 4;
  const int pbase = bh * NSLOT + poff(qb);
  const int col = threadIdx.x & 63, r0 = threadIdx.x >> 6;
#pragma unroll 4
  for (int i = 0; i < 32; ++i) {
    const int row = i * 4 + r0;
    float val = 0.f, l = 0.f;
    for (int s = 0; s < nseg; ++s) {
      val += (float)po[(size_t)(pbase + s) * 128 * 64 + row * 64 + col];
      l += pl[(pbase + s) * 128 + row];
    }
    y[(size_t)(b * T_ + qb * 128 + row) * C_ + h * 64 + col] = (bf16)(val / l);
  }
}

// ---------------------------------------------------------------- launch
extern "C" void kernel_launch(void* const* d_in, const int* in_sizes, int n_in,
                              void* d_out, int out_size, void* d_ws, size_t ws_size,
                              hipStream_t stream) {
  const float* x  = (const float*)d_in[0];
  const float* Wq = (const float*)d_in[1];
  const float* bq = (const float*)d_in[2];
  const float* Wk = (const float*)d_in[3];
  const float* bk = (const float*)d_in[4];
  const float* Wv = (const float*)d_in[5];
  const float* bv = (const float*)d_in[6];
  const float* Wo = (const float*)d_in[7];
  const float* bo = (const float*)d_in[8];

  bf16* ws  = (bf16*)d_ws;
  bf16* WtQ = ws;
  bf16* WtK = WtQ + (size_t)C_ * C_;
  bf16* WtV = WtK + (size_t)C_ * C_;
  bf16* WtO = WtV + (size_t)C_ * C_;
  bf16* xb  = WtO + (size_t)C_ * C_;           // [4096][1024]
  bf16* qkb = xb + (size_t)M_ * C_;            // [4096][2048]  (Q | K)
  bf16* vtb = qkb + (size_t)M_ * 2 * C_;       // [32][64][2048]
  bf16* yb  = vtb + (size_t)M_ * C_;           // [4096][1024]
  bf16* pob = yb + (size_t)M_ * C_;            // [32*36][128][64] partial O
  float* plb = (float*)(pob + (size_t)32 * NSLOT * 128 * 64);

  PrepArgs pp;
  pp.w[0] = Wq; pp.w[1] = Wk; pp.w[2] = Wv; pp.w[3] = Wo;
  pp.wt[0] = WtQ; pp.wt[1] = WtK; pp.wt[2] = WtV; pp.wt[3] = WtO;
  pp.x = x; pp.xb = xb;
  prep<<<dim3(4096 + M_ * C_ / (256 * 8)), 256, 0, stream>>>(pp);

  GQ gq;
  gq.A = xb; gq.Bt = WtQ;
  gq.bias[0] = bq; gq.bias[1] = bk; gq.bias[2] = bv;
  gq.Cout = qkb; gq.vt = vtb; gq.N = 2 * C_; gq.K = C_;
  gemm128<<<dim3(24, 32), 256, 0, stream>>>(gq);

  attn6<<<dim3(32, 40), 256, 0, stream>>>(qkb, vtb, yb, pob, plb);
  combine<<<dim3(32 * 12), 256, 0, stream>>>(pob, plb, yb);

  gemm_out<<<dim3(8, 64), 256, 0, stream>>>(yb, WtO, bo, (float*)d_out);
}

// Round 10
// 216.914 us; speedup vs baseline: 1.1726x; 1.1726x over previous
//
#include <hip/hip_runtime.h>
#include <hip/hip_bf16.h>

typedef __bf16 bf16;
typedef __bf16 bf16x4 __attribute__((ext_vector_type(4)));
typedef __bf16 bf16x8 __attribute__((ext_vector_type(8)));
typedef float floatx4 __attribute__((ext_vector_type(4)));

#define B_ 2
#define T_ 2048
#define C_ 1024
#define H_ 16
#define D_ 64
#define M_ 4096
#define QK_LD 2048

__device__ __forceinline__ void load_lds16(const void* g, void* l) {
  __builtin_amdgcn_global_load_lds(
      (const __attribute__((address_space(1))) unsigned int*)g,
      (__attribute__((address_space(3))) unsigned int*)l, 16, 0, 0);
}

// --------------------------- prep: weight transposes + x convert (one launch)
struct PrepArgs { const float* w[4]; bf16* wt[4]; const float* x; bf16* xb; };

__global__ __launch_bounds__(256)
void prep(PrepArgs p) {
  const int bid = blockIdx.x;
  if (bid < 4096) {
    __shared__ float tile[32][33];
    const int z = bid >> 10, xy = bid & 1023;
    const int bx = xy & 31, by = xy >> 5;
    const float* in = p.w[z];
    bf16* out = p.wt[z];
    int tx = threadIdx.x & 31, ty = threadIdx.x >> 5;
    int n0 = bx * 32, k0 = by * 32;
#pragma unroll
    for (int j = 0; j < 32; j += 8)
      tile[ty + j][tx] = in[(size_t)(k0 + ty + j) * C_ + n0 + tx];
    __syncthreads();
#pragma unroll
    for (int j = 0; j < 32; j += 8)
      out[(size_t)(n0 + ty + j) * C_ + k0 + tx] = (bf16)tile[tx][ty + j];
  } else {
    int i = ((bid - 4096) * 256 + threadIdx.x) * 8;
    float4 a = *(const float4*)(p.x + i);
    float4 b = *(const float4*)(p.x + i + 4);
    bf16x8 o;
    o[0] = (bf16)a.x; o[1] = (bf16)a.y; o[2] = (bf16)a.z; o[3] = (bf16)a.w;
    o[4] = (bf16)b.x; o[5] = (bf16)b.y; o[6] = (bf16)b.z; o[7] = (bf16)b.w;
    *(bf16x8*)(p.xb + i) = o;
  }
}

// ---------------------------------------------------------------- QKV GEMM
struct GQ {
  const bf16* A; const bf16* Bt;
  const float* bias[3];
  bf16* Cout; bf16* vt; int N; int K;
};

__global__ __launch_bounds__(256, 2)
void gemm128(GQ g) {
  __shared__ __align__(16) bf16 As[128 * 64];
  __shared__ __align__(16) bf16 Bs[128 * 64];
  const int tid = threadIdx.x;
  const int wave = tid >> 6, lane = tid & 63;
  const int quad = lane >> 4, l16 = lane & 15;
  const int m0 = blockIdx.y * 128, n0 = blockIdx.x * 128;
  const int wm = (wave >> 1) * 64, wn = (wave & 1) * 64;

  floatx4 acc[4][4] = {};

  int rA[4], cA[4];
#pragma unroll
  for (int t = 0; t < 4; ++t) {
    int pch = (wave * 4 + t) * 64 + lane;
    rA[t] = pch >> 3;
    cA[t] = (pch & 7) ^ (rA[t] & 7);
  }

  for (int k0 = 0; k0 < g.K; k0 += 64) {
    __syncthreads();
#pragma unroll
    for (int t = 0; t < 4; ++t) {
      load_lds16(g.A + (size_t)(m0 + rA[t]) * g.K + k0 + cA[t] * 8,
                 As + (wave * 4 + t) * 512);
      load_lds16(g.Bt + (size_t)(n0 + rA[t]) * g.K + k0 + cA[t] * 8,
                 Bs + (wave * 4 + t) * 512);
    }
    __builtin_amdgcn_s_waitcnt(0x0f70);
    __syncthreads();
#pragma unroll
    for (int s = 0; s < 2; ++s) {
      bf16x8 af[4], bfr[4];
#pragma unroll
      for (int i = 0; i < 4; ++i) {
        int mr = wm + i * 16 + l16;
        af[i] = *(const bf16x8*)(As + ((mr * 8) + ((s * 4 + quad) ^ (mr & 7))) * 8);
        int nr = wn + i * 16 + l16;
        bfr[i] = *(const bf16x8*)(Bs + ((nr * 8) + ((s * 4 + quad) ^ (nr & 7))) * 8);
      }
#pragma unroll
      for (int i = 0; i < 4; ++i)
#pragma unroll
        for (int j = 0; j < 4; ++j)
          acc[i][j] = __builtin_amdgcn_mfma_f32_16x16x32_bf16(af[i], bfr[j],
                                                              acc[i][j], 0, 0, 0);
    }
  }

  const bool vsplit = (n0 >= 2048);
#pragma unroll
  for (int j = 0; j < 4; ++j) {
    int col = n0 + wn + j * 16 + l16;
    const float* bp = g.bias[col >> 10];
    float bv = bp[col & 1023];
    if (vsplit) {
      int cv = col - 2048;  // cv = h*64 + d
      bf16* dst0 = g.vt + ((size_t)((m0 >> 11) * 16 + (cv >> 6)) * 64 + (cv & 63)) * (size_t)T_
                   + (m0 & 2047) + wm + quad * 4;
#pragma unroll
      for (int i = 0; i < 4; ++i) {
        bf16x4 pk;
#pragma unroll
        for (int r = 0; r < 4; ++r) pk[r] = (bf16)(acc[i][j][r] + bv);
        *(bf16x4*)(dst0 + i * 16) = pk;
      }
    } else {
#pragma unroll
      for (int i = 0; i < 4; ++i) {
#pragma unroll
        for (int r = 0; r < 4; ++r) {
          int row = m0 + wm + i * 16 + quad * 4 + r;
          g.Cout[(size_t)row * g.N + col] = (bf16)(acc[i][j][r] + bv);
        }
      }
    }
  }
}

// ---------------------------------------------------------------- out GEMM
__global__ __launch_bounds__(256, 2)
void gemm_out(const bf16* __restrict__ A, const bf16* __restrict__ Bt,
              const float* __restrict__ bias, float* __restrict__ C) {
  __shared__ __align__(16) bf16 As[64 * 64];
  __shared__ __align__(16) bf16 Bs[128 * 64];
  const int tid = threadIdx.x;
  const int wave = tid >> 6, lane = tid & 63;
  const int quad = lane >> 4, l16 = lane & 15;
  const int m0 = blockIdx.y * 64, n0 = blockIdx.x * 128;
  const int wm = (wave >> 1) * 32, wn = (wave & 1) * 64;

  floatx4 acc[2][4] = {};

  int rA[2], cA[2], rB[4], cB[4];
#pragma unroll
  for (int t = 0; t < 2; ++t) {
    int p = t * 256 + tid;
    rA[t] = p >> 3; cA[t] = (p & 7) ^ (rA[t] & 7);
  }
#pragma unroll
  for (int t = 0; t < 4; ++t) {
    int p = t * 256 + tid;
    rB[t] = p >> 3; cB[t] = (p & 7) ^ (rB[t] & 7);
  }

  for (int k0 = 0; k0 < 1024; k0 += 64) {
    __syncthreads();
#pragma unroll
    for (int t = 0; t < 2; ++t)
      load_lds16(A + (size_t)(m0 + rA[t]) * 1024 + k0 + cA[t] * 8,
                 As + t * 2048 + wave * 512);
#pragma unroll
    for (int t = 0; t < 4; ++t)
      load_lds16(Bt + (size_t)(n0 + rB[t]) * 1024 + k0 + cB[t] * 8,
                 Bs + t * 2048 + wave * 512);
    __builtin_amdgcn_s_waitcnt(0x0f70);
    __syncthreads();
#pragma unroll
    for (int s = 0; s < 2; ++s) {
      bf16x8 af[2], bfr[4];
#pragma unroll
      for (int i = 0; i < 2; ++i) {
        int mr = wm + i * 16 + l16;
        af[i] = *(const bf16x8*)(As + ((mr * 8) + ((s * 4 + quad) ^ (mr & 7))) * 8);
      }
#pragma unroll
      for (int j = 0; j < 4; ++j) {
        int nr = wn + j * 16 + l16;
        bfr[j] = *(const bf16x8*)(Bs + ((nr * 8) + ((s * 4 + quad) ^ (nr & 7))) * 8);
      }
#pragma unroll
      for (int i = 0; i < 2; ++i)
#pragma unroll
        for (int j = 0; j < 4; ++j)
          acc[i][j] = __builtin_amdgcn_mfma_f32_16x16x32_bf16(af[i], bfr[j],
                                                              acc[i][j], 0, 0, 0);
    }
  }

#pragma unroll
  for (int j = 0; j < 4; ++j) {
    int col = n0 + wn + j * 16 + l16;
    float bv = bias[col];
#pragma unroll
    for (int i = 0; i < 2; ++i)
#pragma unroll
      for (int r = 0; r < 4; ++r) {
        int row = m0 + wm + i * 16 + quad * 4 + r;
        C[(size_t)row * 1024 + col] = acc[i][j][r] + bv;
      }
  }
}

// ---------------------------------------------------------------- attention
// Fixed-max streaming softmax (per-row ALiBi constant retained; scores
// bounded ~+3 in log2 domain, so P = exp2(v - 14): no running max, no
// shuffle reduce, no alpha rescale).
// grid (32 bh, 24): yy<8 whole qb=yy; yy in [8,16) qb=23-yy seg0 (k [0,qb+1),
// never masked); yy in [16,24) qb=31-yy seg1 (k [qb+1,2qb+2), diagonal).
// CU triples (yy,yy+8,yy+16) sum to 34 iters; 3 blocks/CU (LDS-limited).
// Partial-O stored PACKED: slot[chunk4][tid256][8] -> every bf16x8 store is
// 1 KB dense per wave (full lines, no write amplification).
__global__ __launch_bounds__(256, 3)
void attn7(const bf16* __restrict__ qk, const bf16* __restrict__ vt,
           bf16* __restrict__ y, bf16* __restrict__ po, float* __restrict__ pl) {
  __shared__ __align__(16) bf16 Kl[2][64 * 64];
  __shared__ __align__(16) bf16 Vl[2][64 * 64];
  __shared__ __align__(16) bf16 Pl[4][16 * 68];
  const int tid = threadIdx.x, wave = tid >> 6, lane = tid & 63;
  const int quad = lane >> 4, l16 = lane & 15;
  const int bh = blockIdx.x, b = bh >> 4, h = bh & 15;
  const int yy = blockIdx.y;
  int qb, kbeg, kcnt, seg;
  if (yy < 8)       { qb = yy;      kbeg = 0;      kcnt = 2 * qb + 2; seg = -1; }
  else if (yy < 16) { qb = 23 - yy; kbeg = 0;      kcnt = qb + 1;     seg = 0;  }
  else              { qb = 31 - yy; kbeg = qb + 1; kcnt = qb + 1;     seg = 1;  }

  const float L2E = 1.4426950408889634f;
  const float slope2 = exp2f(-0.5f * (float)(h + 1)) * L2E;  // log2-domain slope
  const float scl2 = 0.125f * L2E;
  const float M0 = 14.0f;  // fixed softmax max (log2 units); scores << 14

  bf16x8 ones;
  {
    bf16 v1 = (l16 == 0) ? (bf16)1.0f : (bf16)0.0f;
#pragma unroll
    for (int j = 0; j < 8; ++j) ones[j] = v1;
  }

  int rS[2], cS[2];
#pragma unroll
  for (int t = 0; t < 2; ++t) {
    int p = t * 256 + tid;
    rS[t] = p >> 3;
    cS[t] = (p & 7) ^ (rS[t] & 7);
  }
  const bf16* kbase = qk + (size_t)b * T_ * QK_LD + 1024 + h * 64;
  const bf16* vbase = vt + (size_t)bh * 64 * T_;

  bf16* Plw = Pl[wave];
  const int q0 = qb * 128;
  const int w0 = q0 + wave * 32;

  bf16x8 qf[2][2];
  float rowoff[2][4];
#pragma unroll
  for (int qt = 0; qt < 2; ++qt) {
#pragma unroll
    for (int s = 0; s < 2; ++s)
      qf[qt][s] = *(const bf16x8*)(qk +
          (size_t)(b * T_ + w0 + qt * 16 + l16) * QK_LD + h * 64 + s * 32 + quad * 8);
#pragma unroll
    for (int r = 0; r < 4; ++r)
      rowoff[qt][r] = slope2 * (float)(w0 + qt * 16 + quad * 4 + r) + M0;
  }

  floatx4 o[2][5];
#pragma unroll
  for (int qt = 0; qt < 2; ++qt)
#pragma unroll
    for (int n = 0; n < 5; ++n) o[qt][n] = (floatx4)0.f;

  // prologue: stage first tile into buffer 0
#pragma unroll
  for (int t = 0; t < 2; ++t) {
    load_lds16(kbase + (size_t)(kbeg * 64 + rS[t]) * QK_LD + cS[t] * 8,
               Kl[0] + (t * 4 + wave) * 512);
    load_lds16(vbase + (size_t)rS[t] * T_ + kbeg * 64 + cS[t] * 8,
               Vl[0] + (t * 4 + wave) * 512);
  }
  __builtin_amdgcn_s_waitcnt(0x0f70);
  __syncthreads();

  for (int it = 0; it < kcnt; ++it) {
    const int kj0 = (kbeg + it) * 64;
    const int cur = it & 1;

    if (it + 1 < kcnt) {
      const int nk = kj0 + 64;
#pragma unroll
      for (int t = 0; t < 2; ++t) {
        load_lds16(kbase + (size_t)(nk + rS[t]) * QK_LD + cS[t] * 8,
                   Kl[cur ^ 1] + (t * 4 + wave) * 512);
        load_lds16(vbase + (size_t)rS[t] * T_ + nk + cS[t] * 8,
                   Vl[cur ^ 1] + (t * 4 + wave) * 512);
      }
    }

    const bf16* Klc = Kl[cur];
    const bf16* Vlc = Vl[cur];
    bf16x8 kf[2][4], vf[2][4];
#pragma unroll
    for (int ss = 0; ss < 2; ++ss)
#pragma unroll
      for (int kt = 0; kt < 4; ++kt) {
        const int krow = kt * 16 + l16;
        kf[ss][kt] = *(const bf16x8*)(Klc + krow * 64 + (((ss * 4 + quad) ^ (krow & 7)) * 8));
        vf[ss][kt] = *(const bf16x8*)(Vlc + krow * 64 + (((ss * 4 + quad) ^ (krow & 7)) * 8));
      }

    float scol[4];
#pragma unroll
    for (int kt = 0; kt < 4; ++kt)
      scol[kt] = slope2 * (float)(kj0 + kt * 16 + l16);

#pragma unroll
    for (int qt = 0; qt < 2; ++qt) {
      const int rb = w0 + qt * 16;
      floatx4 sa[4] = {};
#pragma unroll
      for (int ss = 0; ss < 2; ++ss)
#pragma unroll
        for (int kt = 0; kt < 4; ++kt)
          sa[kt] = __builtin_amdgcn_mfma_f32_16x16x32_bf16(qf[qt][ss], kf[ss][kt],
                                                           sa[kt], 0, 0, 0);

      // P = exp2(scale*s + slope*(col-row) - M0); masked cols -> 0
      if (kj0 + 63 > rb) {
#pragma unroll
        for (int kt = 0; kt < 4; ++kt)
#pragma unroll
          for (int r = 0; r < 4; ++r) {
            const int row = rb + quad * 4 + r;
            float p = __builtin_amdgcn_exp2f(
                fmaf(sa[kt][r], scl2, scol[kt]) - rowoff[qt][r]);
            if (kj0 + kt * 16 + l16 > row) p = 0.f;
            Plw[(quad * 4 + r) * 68 + kt * 16 + l16] = (bf16)p;
          }
      } else {
#pragma unroll
        for (int kt = 0; kt < 4; ++kt)
#pragma unroll
          for (int r = 0; r < 4; ++r)
            Plw[(quad * 4 + r) * 68 + kt * 16 + l16] = (bf16)__builtin_amdgcn_exp2f(
                fmaf(sa[kt][r], scl2, scol[kt]) - rowoff[qt][r]);
      }

      __builtin_amdgcn_s_waitcnt(0xc07f);  // lgkmcnt(0): P visible in-wave

#pragma unroll
      for (int half = 0; half < 2; ++half) {
        bf16x8 pf = *(const bf16x8*)(Plw + l16 * 68 + half * 32 + quad * 8);
#pragma unroll
        for (int nt = 0; nt < 4; ++nt)
          o[qt][nt] = __builtin_amdgcn_mfma_f32_16x16x32_bf16(pf, vf[half][nt],
                                                              o[qt][nt], 0, 0, 0);
        o[qt][4] = __builtin_amdgcn_mfma_f32_16x16x32_bf16(pf, ones, o[qt][4], 0, 0, 0);
      }
    }

    __builtin_amdgcn_s_waitcnt(0x0f70);  // vmcnt(0): next tile landed
    __syncthreads();
  }

  if (seg < 0) {
#pragma unroll
    for (int qt = 0; qt < 2; ++qt)
#pragma unroll
      for (int r = 0; r < 4; ++r) {
        float lsum = __shfl(o[qt][4][r], lane & 48);  // l16==0 lane of this quad
        float inv = 1.f / lsum;
        const int row = w0 + qt * 16 + quad * 4 + r;
#pragma unroll
        for (int nt = 0; nt < 4; ++nt)
          y[(size_t)(b * T_ + row) * C_ + h * 64 + nt * 16 + l16] =
              (bf16)(o[qt][nt][r] * inv);
      }
  } else {
    // packed: slot[chunk=qt*2+half][tid][8], value j=half*8+jj -> nt=j>>2, r=j&3
    const int pid = (bh * 8 + (qb - 8)) * 2 + seg;
    bf16* pob = po + (size_t)pid * 8192;
#pragma unroll
    for (int qt = 0; qt < 2; ++qt) {
#pragma unroll
      for (int half = 0; half < 2; ++half) {
        bf16x8 pk;
#pragma unroll
        for (int jj = 0; jj < 8; ++jj) {
          int j = half * 8 + jj;
          pk[jj] = (bf16)o[qt][j >> 2][j & 3];
        }
        *(bf16x8*)(pob + (qt * 2 + half) * 2048 + tid * 8) = pk;
      }
#pragma unroll
      for (int r = 0; r < 4; ++r)
        if (l16 == 0)
          pl[pid * 128 + wave * 32 + qt * 16 + quad * 4 + r] = o[qt][4][r];
    }
  }
}

// --------------------------------------------------- combine split segments
// grid 32*8 blocks: one per (bh, qb in 8..15).  out = (o0+o1)/(l0+l1).
__global__ __launch_bounds__(256)
void combine(const bf16* __restrict__ po, const float* __restrict__ pl,
             bf16* __restrict__ y) {
  const int x = blockIdx.x;
  const int bh = x >> 3, qb = (x & 7) + 8;
  const int b = bh >> 4, h = bh & 15;
  const int pid0 = (bh * 8 + (qb - 8)) * 2;
  const bf16* p0 = po + (size_t)pid0 * 8192;
  const bf16* p1 = p0 + 8192;
  const int t = threadIdx.x;
  const int wave = t >> 6, quad = (t >> 4) & 3, l16 = t & 15;

  float linv[2][4];
#pragma unroll
  for (int qt = 0; qt < 2; ++qt)
#pragma unroll
    for (int r = 0; r < 4; ++r) {
      const int row = wave * 32 + qt * 16 + quad * 4 + r;
      linv[qt][r] = 1.f / (pl[pid0 * 128 + row] + pl[(pid0 + 1) * 128 + row]);
    }

#pragma unroll
  for (int qt = 0; qt < 2; ++qt)
#pragma unroll
    for (int half = 0; half < 2; ++half) {
      bf16x8 a = *(const bf16x8*)(p0 + (qt * 2 + half) * 2048 + t * 8);
      bf16x8 c = *(const bf16x8*)(p1 + (qt * 2 + half) * 2048 + t * 8);
#pragma unroll
      for (int jj = 0; jj < 8; ++jj) {
        int j = half * 8 + jj;
        const int nt = j >> 2, r = j & 3;
        const int row = wave * 32 + qt * 16 + quad * 4 + r;
        const int col = nt * 16 + l16;
        float v = ((float)a[jj] + (float)c[jj]) * linv[qt][r];
        y[(size_t)(b * T_ + qb * 128 + row) * C_ + h * 64 + col] = (bf16)v;
      }
    }
}

// ---------------------------------------------------------------- launch
extern "C" void kernel_launch(void* const* d_in, const int* in_sizes, int n_in,
                              void* d_out, int out_size, void* d_ws, size_t ws_size,
                              hipStream_t stream) {
  const float* x  = (const float*)d_in[0];
  const float* Wq = (const float*)d_in[1];
  const float* bq = (const float*)d_in[2];
  const float* Wk = (const float*)d_in[3];
  const float* bk = (const float*)d_in[4];
  const float* Wv = (const float*)d_in[5];
  const float* bv = (const float*)d_in[6];
  const float* Wo = (const float*)d_in[7];
  const float* bo = (const float*)d_in[8];

  bf16* ws  = (bf16*)d_ws;
  bf16* WtQ = ws;
  bf16* WtK = WtQ + (size_t)C_ * C_;
  bf16* WtV = WtK + (size_t)C_ * C_;
  bf16* WtO = WtV + (size_t)C_ * C_;
  bf16* xb  = WtO + (size_t)C_ * C_;           // [4096][1024]
  bf16* qkb = xb + (size_t)M_ * C_;            // [4096][2048]  (Q | K)
  bf16* vtb = qkb + (size_t)M_ * 2 * C_;       // [32][64][2048]
  bf16* yb  = vtb + (size_t)M_ * C_;           // [4096][1024]
  bf16* pob = yb + (size_t)M_ * C_;            // [512][8192] packed partial O
  float* plb = (float*)(pob + (size_t)512 * 8192);

  PrepArgs pp;
  pp.w[0] = Wq; pp.w[1] = Wk; pp.w[2] = Wv; pp.w[3] = Wo;
  pp.wt[0] = WtQ; pp.wt[1] = WtK; pp.wt[2] = WtV; pp.wt[3] = WtO;
  pp.x = x; pp.xb = xb;
  prep<<<dim3(4096 + M_ * C_ / (256 * 8)), 256, 0, stream>>>(pp);

  GQ gq;
  gq.A = xb; gq.Bt = WtQ;
  gq.bias[0] = bq; gq.bias[1] = bk; gq.bias[2] = bv;
  gq.Cout = qkb; gq.vt = vtb; gq.N = 2 * C_; gq.K = C_;
  gemm128<<<dim3(24, 32), 256, 0, stream>>>(gq);

  attn7<<<dim3(32, 24), 256, 0, stream>>>(qkb, vtb, yb, pob, plb);
  combine<<<dim3(32 * 8), 256, 0, stream>>>(pob, plb, yb);

  gemm_out<<<dim3(8, 64), 256, 0, stream>>>(yb, WtO, bo, (float*)d_out);
}

// Round 11
// 185.030 us; speedup vs baseline: 1.3747x; 1.1723x over previous
//
#include <hip/hip_runtime.h>
#include <hip/hip_bf16.h>

typedef __bf16 bf16;
typedef __bf16 bf16x4 __attribute__((ext_vector_type(4)));
typedef __bf16 bf16x8 __attribute__((ext_vector_type(8)));
typedef float floatx4 __attribute__((ext_vector_type(4)));

#define B_ 2
#define T_ 2048
#define C_ 1024
#define H_ 16
#define D_ 64
#define M_ 4096
#define QK_LD 2048

__device__ __forceinline__ void load_lds16(const void* g, void* l) {
  __builtin_amdgcn_global_load_lds(
      (const __attribute__((address_space(1))) unsigned int*)g,
      (__attribute__((address_space(3))) unsigned int*)l, 16, 0, 0);
}

// --------------------------- prep: weight transposes + x convert (one launch)
struct PrepArgs { const float* w[4]; bf16* wt[4]; const float* x; bf16* xb; };

__global__ __launch_bounds__(256)
void prep(PrepArgs p) {
  const int bid = blockIdx.x;
  if (bid < 4096) {
    __shared__ float tile[32][33];
    const int z = bid >> 10, xy = bid & 1023;
    const int bx = xy & 31, by = xy >> 5;
    const float* in = p.w[z];
    bf16* out = p.wt[z];
    int tx = threadIdx.x & 31, ty = threadIdx.x >> 5;
    int n0 = bx * 32, k0 = by * 32;
#pragma unroll
    for (int j = 0; j < 32; j += 8)
      tile[ty + j][tx] = in[(size_t)(k0 + ty + j) * C_ + n0 + tx];
    __syncthreads();
#pragma unroll
    for (int j = 0; j < 32; j += 8)
      out[(size_t)(n0 + ty + j) * C_ + k0 + tx] = (bf16)tile[tx][ty + j];
  } else {
    int i = ((bid - 4096) * 256 + threadIdx.x) * 8;
    float4 a = *(const float4*)(p.x + i);
    float4 b = *(const float4*)(p.x + i + 4);
    bf16x8 o;
    o[0] = (bf16)a.x; o[1] = (bf16)a.y; o[2] = (bf16)a.z; o[3] = (bf16)a.w;
    o[4] = (bf16)b.x; o[5] = (bf16)b.y; o[6] = (bf16)b.z; o[7] = (bf16)b.w;
    *(bf16x8*)(p.xb + i) = o;
  }
}

// ---------------------------------------------------------------- QKV GEMM
struct GQ {
  const bf16* A; const bf16* Bt;
  const float* bias[3];
  bf16* Cout; bf16* vt; int N; int K;
};

__global__ __launch_bounds__(256, 2)
void gemm128(GQ g) {
  __shared__ __align__(16) bf16 As[128 * 64];
  __shared__ __align__(16) bf16 Bs[128 * 64];
  const int tid = threadIdx.x;
  const int wave = tid >> 6, lane = tid & 63;
  const int quad = lane >> 4, l16 = lane & 15;
  const int m0 = blockIdx.y * 128, n0 = blockIdx.x * 128;
  const int wm = (wave >> 1) * 64, wn = (wave & 1) * 64;

  floatx4 acc[4][4] = {};

  int rA[4], cA[4];
#pragma unroll
  for (int t = 0; t < 4; ++t) {
    int pch = (wave * 4 + t) * 64 + lane;
    rA[t] = pch >> 3;
    cA[t] = (pch & 7) ^ (rA[t] & 7);
  }

  for (int k0 = 0; k0 < g.K; k0 += 64) {
    __syncthreads();
#pragma unroll
    for (int t = 0; t < 4; ++t) {
      load_lds16(g.A + (size_t)(m0 + rA[t]) * g.K + k0 + cA[t] * 8,
                 As + (wave * 4 + t) * 512);
      load_lds16(g.Bt + (size_t)(n0 + rA[t]) * g.K + k0 + cA[t] * 8,
                 Bs + (wave * 4 + t) * 512);
    }
    __builtin_amdgcn_s_waitcnt(0x0f70);
    __syncthreads();
#pragma unroll
    for (int s = 0; s < 2; ++s) {
      bf16x8 af[4], bfr[4];
#pragma unroll
      for (int i = 0; i < 4; ++i) {
        int mr = wm + i * 16 + l16;
        af[i] = *(const bf16x8*)(As + ((mr * 8) + ((s * 4 + quad) ^ (mr & 7))) * 8);
        int nr = wn + i * 16 + l16;
        bfr[i] = *(const bf16x8*)(Bs + ((nr * 8) + ((s * 4 + quad) ^ (nr & 7))) * 8);
      }
#pragma unroll
      for (int i = 0; i < 4; ++i)
#pragma unroll
        for (int j = 0; j < 4; ++j)
          acc[i][j] = __builtin_amdgcn_mfma_f32_16x16x32_bf16(af[i], bfr[j],
                                                              acc[i][j], 0, 0, 0);
    }
  }

  const bool vsplit = (n0 >= 2048);
#pragma unroll
  for (int j = 0; j < 4; ++j) {
    int col = n0 + wn + j * 16 + l16;
    const float* bp = g.bias[col >> 10];
    float bv = bp[col & 1023];
    if (vsplit) {
      int cv = col - 2048;  // cv = h*64 + d
      bf16* dst0 = g.vt + ((size_t)((m0 >> 11) * 16 + (cv >> 6)) * 64 + (cv & 63)) * (size_t)T_
                   + (m0 & 2047) + wm + quad * 4;
#pragma unroll
      for (int i = 0; i < 4; ++i) {
        bf16x4 pk;
#pragma unroll
        for (int r = 0; r < 4; ++r) pk[r] = (bf16)(acc[i][j][r] + bv);
        *(bf16x4*)(dst0 + i * 16) = pk;
      }
    } else {
#pragma unroll
      for (int i = 0; i < 4; ++i) {
#pragma unroll
        for (int r = 0; r < 4; ++r) {
          int row = m0 + wm + i * 16 + quad * 4 + r;
          g.Cout[(size_t)row * g.N + col] = (bf16)(acc[i][j][r] + bv);
        }
      }
    }
  }
}

// ---------------------------------------------------------------- out GEMM
__global__ __launch_bounds__(256, 2)
void gemm_out(const bf16* __restrict__ A, const bf16* __restrict__ Bt,
              const float* __restrict__ bias, float* __restrict__ C) {
  __shared__ __align__(16) bf16 As[64 * 64];
  __shared__ __align__(16) bf16 Bs[128 * 64];
  const int tid = threadIdx.x;
  const int wave = tid >> 6, lane = tid & 63;
  const int quad = lane >> 4, l16 = lane & 15;
  const int m0 = blockIdx.y * 64, n0 = blockIdx.x * 128;
  const int wm = (wave >> 1) * 32, wn = (wave & 1) * 64;

  floatx4 acc[2][4] = {};

  int rA[2], cA[2], rB[4], cB[4];
#pragma unroll
  for (int t = 0; t < 2; ++t) {
    int p = t * 256 + tid;
    rA[t] = p >> 3; cA[t] = (p & 7) ^ (rA[t] & 7);
  }
#pragma unroll
  for (int t = 0; t < 4; ++t) {
    int p = t * 256 + tid;
    rB[t] = p >> 3; cB[t] = (p & 7) ^ (rB[t] & 7);
  }

  for (int k0 = 0; k0 < 1024; k0 += 64) {
    __syncthreads();
#pragma unroll
    for (int t = 0; t < 2; ++t)
      load_lds16(A + (size_t)(m0 + rA[t]) * 1024 + k0 + cA[t] * 8,
                 As + t * 2048 + wave * 512);
#pragma unroll
    for (int t = 0; t < 4; ++t)
      load_lds16(Bt + (size_t)(n0 + rB[t]) * 1024 + k0 + cB[t] * 8,
                 Bs + t * 2048 + wave * 512);
    __builtin_amdgcn_s_waitcnt(0x0f70);
    __syncthreads();
#pragma unroll
    for (int s = 0; s < 2; ++s) {
      bf16x8 af[2], bfr[4];
#pragma unroll
      for (int i = 0; i < 2; ++i) {
        int mr = wm + i * 16 + l16;
        af[i] = *(const bf16x8*)(As + ((mr * 8) + ((s * 4 + quad) ^ (mr & 7))) * 8);
      }
#pragma unroll
      for (int j = 0; j < 4; ++j) {
        int nr = wn + j * 16 + l16;
        bfr[j] = *(const bf16x8*)(Bs + ((nr * 8) + ((s * 4 + quad) ^ (nr & 7))) * 8);
      }
#pragma unroll
      for (int i = 0; i < 2; ++i)
#pragma unroll
        for (int j = 0; j < 4; ++j)
          acc[i][j] = __builtin_amdgcn_mfma_f32_16x16x32_bf16(af[i], bfr[j],
                                                              acc[i][j], 0, 0, 0);
    }
  }

#pragma unroll
  for (int j = 0; j < 4; ++j) {
    int col = n0 + wn + j * 16 + l16;
    float bv = bias[col];
#pragma unroll
    for (int i = 0; i < 2; ++i)
#pragma unroll
      for (int r = 0; r < 4; ++r) {
        int row = m0 + wm + i * 16 + quad * 4 + r;
        C[(size_t)row * 1024 + col] = acc[i][j][r] + bv;
      }
  }
}

// ---------------------------------------------------------------- attention
// Fixed-max streaming softmax (per-row ALiBi constant retained; scores
// bounded ~+3 in log2 domain, so P = exp2(v - 14): no running max, no
// shuffle reduce, no alpha rescale).
// grid (32 bh, 24): yy<8 whole qb=yy; yy in [8,16) qb=23-yy seg0 (k [0,qb+1),
// never masked); yy in [16,24) qb=31-yy seg1 (k [qb+1,2qb+2), diagonal).
// __launch_bounds__(256,2): 2 blocks/CU — lb3 trashed L2 (FETCH 12->29 MB,
// K/V loads became HBM misses that dbuf can't hide; R9/R10 evidence).
// Partial-O stored packed: slot[chunk4][tid256][8] (1 KB dense per wave).
__global__ __launch_bounds__(256, 2)
void attn8(const bf16* __restrict__ qk, const bf16* __restrict__ vt,
           bf16* __restrict__ y, bf16* __restrict__ po, float* __restrict__ pl) {
  __shared__ __align__(16) bf16 Kl[2][64 * 64];
  __shared__ __align__(16) bf16 Vl[2][64 * 64];
  __shared__ __align__(16) bf16 Pl[4][16 * 68];
  const int tid = threadIdx.x, wave = tid >> 6, lane = tid & 63;
  const int quad = lane >> 4, l16 = lane & 15;
  const int bh = blockIdx.x, b = bh >> 4, h = bh & 15;
  const int yy = blockIdx.y;
  int qb, kbeg, kcnt, seg;
  if (yy < 8)       { qb = yy;      kbeg = 0;      kcnt = 2 * qb + 2; seg = -1; }
  else if (yy < 16) { qb = 23 - yy; kbeg = 0;      kcnt = qb + 1;     seg = 0;  }
  else              { qb = 31 - yy; kbeg = qb + 1; kcnt = qb + 1;     seg = 1;  }

  const float L2E = 1.4426950408889634f;
  const float slope2 = exp2f(-0.5f * (float)(h + 1)) * L2E;  // log2-domain slope
  const float scl2 = 0.125f * L2E;
  const float M0 = 14.0f;  // fixed softmax max (log2 units); scores << 14

  bf16x8 ones;
  {
    bf16 v1 = (l16 == 0) ? (bf16)1.0f : (bf16)0.0f;
#pragma unroll
    for (int j = 0; j < 8; ++j) ones[j] = v1;
  }

  int rS[2], cS[2];
#pragma unroll
  for (int t = 0; t < 2; ++t) {
    int p = t * 256 + tid;
    rS[t] = p >> 3;
    cS[t] = (p & 7) ^ (rS[t] & 7);
  }
  const bf16* kbase = qk + (size_t)b * T_ * QK_LD + 1024 + h * 64;
  const bf16* vbase = vt + (size_t)bh * 64 * T_;

  bf16* Plw = Pl[wave];
  const int q0 = qb * 128;
  const int w0 = q0 + wave * 32;

  bf16x8 qf[2][2];
  float rowoff[2][4];
#pragma unroll
  for (int qt = 0; qt < 2; ++qt) {
#pragma unroll
    for (int s = 0; s < 2; ++s)
      qf[qt][s] = *(const bf16x8*)(qk +
          (size_t)(b * T_ + w0 + qt * 16 + l16) * QK_LD + h * 64 + s * 32 + quad * 8);
#pragma unroll
    for (int r = 0; r < 4; ++r)
      rowoff[qt][r] = slope2 * (float)(w0 + qt * 16 + quad * 4 + r) + M0;
  }

  floatx4 o[2][5];
#pragma unroll
  for (int qt = 0; qt < 2; ++qt)
#pragma unroll
    for (int n = 0; n < 5; ++n) o[qt][n] = (floatx4)0.f;

  // prologue: stage first tile into buffer 0
#pragma unroll
  for (int t = 0; t < 2; ++t) {
    load_lds16(kbase + (size_t)(kbeg * 64 + rS[t]) * QK_LD + cS[t] * 8,
               Kl[0] + (t * 4 + wave) * 512);
    load_lds16(vbase + (size_t)rS[t] * T_ + kbeg * 64 + cS[t] * 8,
               Vl[0] + (t * 4 + wave) * 512);
  }
  __builtin_amdgcn_s_waitcnt(0x0f70);
  __syncthreads();

  for (int it = 0; it < kcnt; ++it) {
    const int kj0 = (kbeg + it) * 64;
    const int cur = it & 1;

    if (it + 1 < kcnt) {
      const int nk = kj0 + 64;
#pragma unroll
      for (int t = 0; t < 2; ++t) {
        load_lds16(kbase + (size_t)(nk + rS[t]) * QK_LD + cS[t] * 8,
                   Kl[cur ^ 1] + (t * 4 + wave) * 512);
        load_lds16(vbase + (size_t)rS[t] * T_ + nk + cS[t] * 8,
                   Vl[cur ^ 1] + (t * 4 + wave) * 512);
      }
    }

    const bf16* Klc = Kl[cur];
    const bf16* Vlc = Vl[cur];
    bf16x8 kf[2][4], vf[2][4];
#pragma unroll
    for (int ss = 0; ss < 2; ++ss)
#pragma unroll
      for (int kt = 0; kt < 4; ++kt) {
        const int krow = kt * 16 + l16;
        kf[ss][kt] = *(const bf16x8*)(Klc + krow * 64 + (((ss * 4 + quad) ^ (krow & 7)) * 8));
        vf[ss][kt] = *(const bf16x8*)(Vlc + krow * 64 + (((ss * 4 + quad) ^ (krow & 7)) * 8));
      }

    float scol[4];
#pragma unroll
    for (int kt = 0; kt < 4; ++kt)
      scol[kt] = slope2 * (float)(kj0 + kt * 16 + l16);

#pragma unroll
    for (int qt = 0; qt < 2; ++qt) {
      const int rb = w0 + qt * 16;
      floatx4 sa[4] = {};
#pragma unroll
      for (int ss = 0; ss < 2; ++ss)
#pragma unroll
        for (int kt = 0; kt < 4; ++kt)
          sa[kt] = __builtin_amdgcn_mfma_f32_16x16x32_bf16(qf[qt][ss], kf[ss][kt],
                                                           sa[kt], 0, 0, 0);

      // P = exp2(scale*s + slope*(col-row) - M0); masked cols -> 0
      if (kj0 + 63 > rb) {
#pragma unroll
        for (int kt = 0; kt < 4; ++kt)
#pragma unroll
          for (int r = 0; r < 4; ++r) {
            const int row = rb + quad * 4 + r;
            float p = __builtin_amdgcn_exp2f(
                fmaf(sa[kt][r], scl2, scol[kt]) - rowoff[qt][r]);
            if (kj0 + kt * 16 + l16 > row) p = 0.f;
            Plw[(quad * 4 + r) * 68 + kt * 16 + l16] = (bf16)p;
          }
      } else {
#pragma unroll
        for (int kt = 0; kt < 4; ++kt)
#pragma unroll
          for (int r = 0; r < 4; ++r)
            Plw[(quad * 4 + r) * 68 + kt * 16 + l16] = (bf16)__builtin_amdgcn_exp2f(
                fmaf(sa[kt][r], scl2, scol[kt]) - rowoff[qt][r]);
      }

      __builtin_amdgcn_s_waitcnt(0xc07f);  // lgkmcnt(0): P visible in-wave

#pragma unroll
      for (int half = 0; half < 2; ++half) {
        bf16x8 pf = *(const bf16x8*)(Plw + l16 * 68 + half * 32 + quad * 8);
#pragma unroll
        for (int nt = 0; nt < 4; ++nt)
          o[qt][nt] = __builtin_amdgcn_mfma_f32_16x16x32_bf16(pf, vf[half][nt],
                                                              o[qt][nt], 0, 0, 0);
        o[qt][4] = __builtin_amdgcn_mfma_f32_16x16x32_bf16(pf, ones, o[qt][4], 0, 0, 0);
      }
    }

    __builtin_amdgcn_s_waitcnt(0x0f70);  // vmcnt(0): next tile landed
    __syncthreads();
  }

  if (seg < 0) {
#pragma unroll
    for (int qt = 0; qt < 2; ++qt)
#pragma unroll
      for (int r = 0; r < 4; ++r) {
        float lsum = __shfl(o[qt][4][r], lane & 48);  // l16==0 lane of this quad
        float inv = 1.f / lsum;
        const int row = w0 + qt * 16 + quad * 4 + r;
#pragma unroll
        for (int nt = 0; nt < 4; ++nt)
          y[(size_t)(b * T_ + row) * C_ + h * 64 + nt * 16 + l16] =
              (bf16)(o[qt][nt][r] * inv);
      }
  } else {
    // packed: slot[chunk=qt*2+half][tid][8], value j=half*8+jj -> nt=j>>2, r=j&3
    const int pid = (bh * 8 + (qb - 8)) * 2 + seg;
    bf16* pob = po + (size_t)pid * 8192;
#pragma unroll
    for (int qt = 0; qt < 2; ++qt) {
#pragma unroll
      for (int half = 0; half < 2; ++half) {
        bf16x8 pk;
#pragma unroll
        for (int jj = 0; jj < 8; ++jj) {
          int j = half * 8 + jj;
          pk[jj] = (bf16)o[qt][j >> 2][j & 3];
        }
        *(bf16x8*)(pob + (qt * 2 + half) * 2048 + tid * 8) = pk;
      }
#pragma unroll
      for (int r = 0; r < 4; ++r)
        if (l16 == 0)
          pl[pid * 128 + wave * 32 + qt * 16 + quad * 4 + r] = o[qt][4][r];
    }
  }
}

// --------------------------------------------------- combine split segments
// grid 32*8 blocks: one per (bh, qb in 8..15).  out = (o0+o1)/(l0+l1).
__global__ __launch_bounds__(256)
void combine(const bf16* __restrict__ po, const float* __restrict__ pl,
             bf16* __restrict__ y) {
  const int x = blockIdx.x;
  const int bh = x >> 3, qb = (x & 7) + 8;
  const int b = bh >> 4, h = bh & 15;
  const int pid0 = (bh * 8 + (qb - 8)) * 2;
  const bf16* p0 = po + (size_t)pid0 * 8192;
  const bf16* p1 = p0 + 8192;
  const int t = threadIdx.x;
  const int wave = t >> 6, quad = (t >> 4) & 3, l16 = t & 15;

  float linv[2][4];
#pragma unroll
  for (int qt = 0; qt < 2; ++qt)
#pragma unroll
    for (int r = 0; r < 4; ++r) {
      const int row = wave * 32 + qt * 16 + quad * 4 + r;
      linv[qt][r] = 1.f / (pl[pid0 * 128 + row] + pl[(pid0 + 1) * 128 + row]);
    }

#pragma unroll
  for (int qt = 0; qt < 2; ++qt)
#pragma unroll
    for (int half = 0; half < 2; ++half) {
      bf16x8 a = *(const bf16x8*)(p0 + (qt * 2 + half) * 2048 + t * 8);
      bf16x8 c = *(const bf16x8*)(p1 + (qt * 2 + half) * 2048 + t * 8);
#pragma unroll
      for (int jj = 0; jj < 8; ++jj) {
        int j = half * 8 + jj;
        const int nt = j >> 2, r = j & 3;
        const int row = wave * 32 + qt * 16 + quad * 4 + r;
        const int col = nt * 16 + l16;
        float v = ((float)a[jj] + (float)c[jj]) * linv[qt][r];
        y[(size_t)(b * T_ + qb * 128 + row) * C_ + h * 64 + col] = (bf16)v;
      }
    }
}

// ---------------------------------------------------------------- launch
extern "C" void kernel_launch(void* const* d_in, const int* in_sizes, int n_in,
                              void* d_out, int out_size, void* d_ws, size_t ws_size,
                              hipStream_t stream) {
  const float* x  = (const float*)d_in[0];
  const float* Wq = (const float*)d_in[1];
  const float* bq = (const float*)d_in[2];
  const float* Wk = (const float*)d_in[3];
  const float* bk = (const float*)d_in[4];
  const float* Wv = (const float*)d_in[5];
  const float* bv = (const float*)d_in[6];
  const float* Wo = (const float*)d_in[7];
  const float* bo = (const float*)d_in[8];

  bf16* ws  = (bf16*)d_ws;
  bf16* WtQ = ws;
  bf16* WtK = WtQ + (size_t)C_ * C_;
  bf16* WtV = WtK + (size_t)C_ * C_;
  bf16* WtO = WtV + (size_t)C_ * C_;
  bf16* xb  = WtO + (size_t)C_ * C_;           // [4096][1024]
  bf16* qkb = xb + (size_t)M_ * C_;            // [4096][2048]  (Q | K)
  bf16* vtb = qkb + (size_t)M_ * 2 * C_;       // [32][64][2048]
  bf16* yb  = vtb + (size_t)M_ * C_;           // [4096][1024]
  bf16* pob = yb + (size_t)M_ * C_;            // [512][8192] packed partial O
  float* plb = (float*)(pob + (size_t)512 * 8192);

  PrepArgs pp;
  pp.w[0] = Wq; pp.w[1] = Wk; pp.w[2] = Wv; pp.w[3] = Wo;
  pp.wt[0] = WtQ; pp.wt[1] = WtK; pp.wt[2] = WtV; pp.wt[3] = WtO;
  pp.x = x; pp.xb = xb;
  prep<<<dim3(4096 + M_ * C_ / (256 * 8)), 256, 0, stream>>>(pp);

  GQ gq;
  gq.A = xb; gq.Bt = WtQ;
  gq.bias[0] = bq; gq.bias[1] = bk; gq.bias[2] = bv;
  gq.Cout = qkb; gq.vt = vtb; gq.N = 2 * C_; gq.K = C_;
  gemm128<<<dim3(24, 32), 256, 0, stream>>>(gq);

  attn8<<<dim3(32, 24), 256, 0, stream>>>(qkb, vtb, yb, pob, plb);
  combine<<<dim3(32 * 8), 256, 0, stream>>>(pob, plb, yb);

  gemm_out<<<dim3(8, 64), 256, 0, stream>>>(yb, WtO, bo, (float*)d_out);
}